// Round 1
// baseline (13334.663 us; speedup 1.0000x reference)
//
#include <hip/hip_runtime.h>
#include <stdint.h>

#define T_STEPS 320
#define BATCH   192
#define HID     1024
#define NBLK    256
#define NBLK_DIR 128

typedef unsigned short u16;
typedef __bf16 bf16x8 __attribute__((ext_vector_type(8)));
typedef float  f32x4  __attribute__((ext_vector_type(4)));

// ---------------- workspace layout (bytes) ----------------
#define OFF_LOGITS   0u          // [192][320] f32 = 245760
#define OFF_BAR      245760u     // 4 x u32 barrier (cntF genF cntB genB)
#define MEMSET_BYTES 245776u
#define OFF_C0       262144u     // [2][192][1024] f32 = 1572864
#define OFF_H        1835008u    // [2 dir][2 buf][192][1024] bf16 = 1572864
#define OFF_WPACK    3407872u    // packed W_hh bf16 fragments = 16777216
#define OFF_COEF     20185088u   // [2][64][64] float4 (w0,w1,bias,0) = 131072
#define WS_NEED      20316160u

__device__ __forceinline__ u16 f2bf(float f) {
  unsigned u = __float_as_uint(f);
  unsigned r = (u + 0x7FFFu + ((u >> 16) & 1u)) >> 16;
  return (u16)r;
}
__device__ __forceinline__ float sigm(float x)   { return 1.f / (1.f + __expf(-x)); }
__device__ __forceinline__ float tanh_f(float x) { return 1.f - 2.f / (1.f + __expf(2.f * x)); }

// ---------------- prep: pack W_hh into MFMA-fragment order (bf16) ----------------
// block slice: dir (1b), jsl (64), per slice: [ks 0..31][cg 0..3][lane 0..63][8 elems]
// col(c 0..63) -> gate = c&3, hidden jj = c>>2 ; W row R = gate*1024 + jsl*16 + jj
__global__ void pack_k(const float* __restrict__ Whhf, const float* __restrict__ Whhb,
                       u16* __restrict__ wpack)
{
  int lin = blockIdx.x * 256 + threadIdx.x;      // < 1048576
  int lane = lin & 63;
  int cg   = (lin >> 6) & 3;
  int ks   = (lin >> 8) & 31;
  int jsl  = (lin >> 13) & 63;
  int dir  = (lin >> 19) & 1;
  int col  = cg * 16 + (lane & 15);
  int R    = (col & 3) * 1024 + jsl * 16 + (col >> 2);
  int kb   = ks * 32 + (lane >> 4) * 8;
  const float* W = dir ? Whhb : Whhf;
  const float* src = W + (size_t)R * 1024 + kb;
  unsigned w[4];
  #pragma unroll
  for (int e = 0; e < 4; ++e) {
    unsigned lo = f2bf(src[2 * e]);
    unsigned hi = f2bf(src[2 * e + 1]);
    w[e] = lo | (hi << 16);
  }
  *((uint4*)(wpack + (size_t)lin * 8)) = make_uint4(w[0], w[1], w[2], w[3]);
}

// ---------------- prep: per-gate-row x-projection coefficients ----------------
__global__ void coef_k(const float* __restrict__ Wihf, const float* __restrict__ bihf,
                       const float* __restrict__ bhhf,
                       const float* __restrict__ Wihb, const float* __restrict__ bihb,
                       const float* __restrict__ bhhb, float* __restrict__ coef)
{
  int id  = blockIdx.x * 256 + threadIdx.x;      // < 8192
  int col = id & 63;
  int jsl = (id >> 6) & 63;
  int dir = (id >> 12) & 1;
  int R   = (col & 3) * 1024 + jsl * 16 + (col >> 2);
  const float* Wih = dir ? Wihb : Wihf;
  const float* bi  = dir ? bihb : bihf;
  const float* bh  = dir ? bhhb : bhhf;
  float4 v;
  v.x = Wih[(size_t)R * 2 + 0];
  v.y = Wih[(size_t)R * 2 + 1];
  v.z = bi[R] + bh[R];
  v.w = 0.f;
  ((float4*)coef)[id] = v;
}

// ---------------- prep: h0/c0 projections (tanh(latent @ W^T + b)) ----------------
__global__ void init_k(const float* __restrict__ ctrl, const float* __restrict__ ratw,
                       const float* __restrict__ Whf, const float* __restrict__ bhf,
                       const float* __restrict__ Whb, const float* __restrict__ bhb,
                       const float* __restrict__ Wcf, const float* __restrict__ bcf,
                       const float* __restrict__ Wcb, const float* __restrict__ bcb,
                       u16* hb, float* c0)
{
  int idx = blockIdx.x * 256 + threadIdx.x;      // 0..196607
  int m = blockIdx.y;                             // 0 h0f, 1 h0b, 2 c0f, 3 c0b
  int b = idx >> 10;
  int h = idx & 1023;
  const float* W  = (m == 0) ? Whf : (m == 1) ? Whb : (m == 2) ? Wcf : Wcb;
  const float* bi = (m == 0) ? bhf : (m == 1) ? bhb : (m == 2) ? bcf : bcb;
  float acc = bi[h];
  const float* wr = W + h * 24;
  #pragma unroll
  for (int k = 0; k < 16; ++k) acc += wr[k] * ctrl[b * 16 + k];
  #pragma unroll
  for (int k = 0; k < 8; ++k)  acc += wr[16 + k] * ratw[b * 8 + k];
  acc = tanh_f(acc);
  if (m < 2) hb[((size_t)(m * 2 + 0) * BATCH + b) * HID + h] = f2bf(acc);
  else       c0[((size_t)(m - 2) * BATCH + b) * HID + h] = acc;
}

// ---------------- persistent bi-LSTM ----------------
// 256 blocks: dir = bid>>7, bhalf = (bid>>6)&1 (so XCD partners share a W slice), jsl = bid&63
// block output tile: 96 batch x 64 gate-cols, K=1024; 4 waves 2x2 (wm rows48, wn cols32)
__launch_bounds__(256, 1)
__global__ void lstm_persist(const float* __restrict__ x,
                             const float* __restrict__ wlog,
                             float* logits,
                             const float* __restrict__ c0,
                             u16* hb,
                             const u16* __restrict__ wpack,
                             const float* __restrict__ coef,
                             unsigned* bar)
{
  extern __shared__ char lds[];
  u16*   Wlds = (u16*)lds;                    // [32 ks][4 cg][64 lane][8] bf16 = 128 KiB
  float* gbuf = (float*)(lds + 131072);       // [4 waves][48][36] f32 = 27648 B
  int*   ldsflag = (int*)(lds + 131072 + 27648);

  const int tid   = threadIdx.x;
  const int bid   = blockIdx.x;
  const int dir   = bid >> 7;
  const int bhalf = (bid >> 6) & 1;
  const int jsl   = bid & 63;
  const int wave  = tid >> 6;
  const int lane  = tid & 63;
  const int wm    = wave >> 1, wn = wave & 1;

  if (tid == 0) *ldsflag = 0;

  { // W slice -> LDS once
    const uint4* wsrc = (const uint4*)wpack + (size_t)(dir * 64 + jsl) * 8192;
    uint4* wdst = (uint4*)Wlds;
    for (int i = tid; i < 8192; i += 256) wdst[i] = wsrc[i];
  }

  const int jj    = lane & 7;                  // hidden-within-wave (0..7)
  const int jglob = jsl * 16 + wn * 8 + jj;
  float4 cf0, cf1, cf2, cf3;
  {
    const float4* cp = (const float4*)coef + ((dir * 64 + jsl) * 64 + wn * 32 + jj * 4);
    cf0 = cp[0]; cf1 = cp[1]; cf2 = cp[2]; cf3 = cp[3];
  }
  const float wlg = wlog[dir * 1024 + jglob];

  float creg[6];
  int   bgl[6];
  #pragma unroll
  for (int i = 0; i < 6; ++i) {
    int q = lane + 64 * i;
    int b_loc = q >> 3;
    int bg = bhalf * 96 + wm * 48 + b_loc;
    bgl[i]  = bg;
    creg[i] = c0[((size_t)dir * BATCH + bg) * HID + jglob];
  }

  int arow[3];
  #pragma unroll
  for (int mt = 0; mt < 3; ++mt) arow[mt] = bhalf * 96 + wm * 48 + mt * 16 + (lane & 15);
  const int kofs = (lane >> 4) * 8;

  unsigned* cnt = bar + dir * 2;
  unsigned* gen = bar + dir * 2 + 1;

  __syncthreads();

  for (int s = 0; s < T_STEPS; ++s) {
    const int rbuf = s & 1;
    const u16* hsrc = hb + ((size_t)(dir * 2 + rbuf)) * BATCH * HID;
    u16*       hdst = hb + ((size_t)(dir * 2 + (rbuf ^ 1))) * BATCH * HID;

    f32x4 acc[3][2];
    #pragma unroll
    for (int mt = 0; mt < 3; ++mt) {
      acc[mt][0] = (f32x4){0.f, 0.f, 0.f, 0.f};
      acc[mt][1] = (f32x4){0.f, 0.f, 0.f, 0.f};
    }

    uint4  aR[4][3];
    bf16x8 bR[2][2];
    #pragma unroll
    for (int mt = 0; mt < 3; ++mt) {
      aR[0][mt] = *(const uint4*)(hsrc + (size_t)arow[mt] * HID + 0 * 32 + kofs);
      aR[1][mt] = *(const uint4*)(hsrc + (size_t)arow[mt] * HID + 1 * 32 + kofs);
    }
    bR[0][0] = *(const bf16x8*)(Wlds + ((0 * 4 + wn * 2 + 0) * 64 + lane) * 8);
    bR[0][1] = *(const bf16x8*)(Wlds + ((0 * 4 + wn * 2 + 1) * 64 + lane) * 8);

    #pragma unroll
    for (int ks = 0; ks < 32; ++ks) {
      if (ks + 2 < 32) {
        #pragma unroll
        for (int mt = 0; mt < 3; ++mt)
          aR[(ks + 2) & 3][mt] =
              *(const uint4*)(hsrc + (size_t)arow[mt] * HID + (ks + 2) * 32 + kofs);
      }
      if (ks + 1 < 32) {
        bR[(ks + 1) & 1][0] = *(const bf16x8*)(Wlds + (((ks + 1) * 4 + wn * 2 + 0) * 64 + lane) * 8);
        bR[(ks + 1) & 1][1] = *(const bf16x8*)(Wlds + (((ks + 1) * 4 + wn * 2 + 1) * 64 + lane) * 8);
      }
      #pragma unroll
      for (int mt = 0; mt < 3; ++mt) {
        bf16x8 a = __builtin_bit_cast(bf16x8, aR[ks & 3][mt]);
        acc[mt][0] = __builtin_amdgcn_mfma_f32_16x16x32_bf16(a, bR[ks & 1][0], acc[mt][0], 0, 0, 0);
        acc[mt][1] = __builtin_amdgcn_mfma_f32_16x16x32_bf16(a, bR[ks & 1][1], acc[mt][1], 0, 0, 0);
      }
    }

    // D -> wave-local LDS transpose (rows: (lane>>4)*4+r, cols: lane&15)
    float* gb = gbuf + wave * (48 * 36);
    #pragma unroll
    for (int mt = 0; mt < 3; ++mt)
      #pragma unroll
      for (int cgi = 0; cgi < 2; ++cgi)
        #pragma unroll
        for (int r = 0; r < 4; ++r)
          gb[(mt * 16 + (lane >> 4) * 4 + r) * 36 + cgi * 16 + (lane & 15)] = acc[mt][cgi][r];

    const int t_x = dir ? (T_STEPS - 1 - s) : s;

    #pragma unroll
    for (int i = 0; i < 6; ++i) {
      int q = lane + 64 * i;
      int b_loc = q >> 3;
      int bg = bgl[i];
      float4 g4 = *(const float4*)(gb + b_loc * 36 + jj * 4);   // (i,f,g,o)
      float2 xv = *(const float2*)(x + ((size_t)t_x * BATCH + bg) * 2);
      float pi = g4.x + cf0.x * xv.x + cf0.y * xv.y + cf0.z;
      float pf = g4.y + cf1.x * xv.x + cf1.y * xv.y + cf1.z;
      float pg = g4.z + cf2.x * xv.x + cf2.y * xv.y + cf2.z;
      float po = g4.w + cf3.x * xv.x + cf3.y * xv.y + cf3.z;
      float ig = sigm(pi), fg = sigm(pf), gv = tanh_f(pg), og = sigm(po);
      float c = fg * creg[i] + ig * gv;
      creg[i] = c;
      float h = og * tanh_f(c);
      hdst[(size_t)bg * HID + jglob] = f2bf(h);
      float lp = h * wlg;
      lp += __shfl_xor(lp, 1);
      lp += __shfl_xor(lp, 2);
      lp += __shfl_xor(lp, 4);
      if (jj == 0) atomicAdd(&logits[bg * T_STEPS + t_x], lp);
    }

    // per-direction grid barrier (128 blocks)
    __syncthreads();
    if (tid == 0) {
      __threadfence();   // release h stores device-wide
      unsigned g = __hip_atomic_load(gen, __ATOMIC_RELAXED, __HIP_MEMORY_SCOPE_AGENT);
      unsigned old = __hip_atomic_fetch_add(cnt, 1u, __ATOMIC_RELAXED, __HIP_MEMORY_SCOPE_AGENT);
      if (old == NBLK_DIR - 1) {
        __hip_atomic_store(cnt, 0u, __ATOMIC_RELAXED, __HIP_MEMORY_SCOPE_AGENT);
        __hip_atomic_fetch_add(gen, 1u, __ATOMIC_RELEASE, __HIP_MEMORY_SCOPE_AGENT);
      } else {
        long guard = 0;
        while (__hip_atomic_load(gen, __ATOMIC_RELAXED, __HIP_MEMORY_SCOPE_AGENT) == g) {
          if (++guard > 20000000L) { *ldsflag = 1; break; }
        }
      }
      __threadfence();   // acquire remote h stores
    }
    __syncthreads();
    if (*ldsflag) return;   // co-residency failure: fail cleanly instead of hanging
  }
}

// ---------------- post: softmax -> cumsum -> rational Bezier -> curves + reg ----------------
__global__ void post_k(const float* __restrict__ logits, const float* __restrict__ ctrl,
                       const float* __restrict__ ratw, float* __restrict__ out)
{
  __shared__ float sh[T_STEPS + 64];
  const int b = blockIdx.x;
  const int t = threadIdx.x;          // 320 threads
  float l = logits[b * T_STEPS + t];
  sh[t] = l;
  __syncthreads();
  if (t < 64) {
    float mm = sh[t];
    for (int i = t + 64; i < T_STEPS; i += 64) mm = fmaxf(mm, sh[i]);
    #pragma unroll
    for (int o = 32; o; o >>= 1) mm = fmaxf(mm, __shfl_xor(mm, o));
    if (t == 0) sh[T_STEPS] = mm;
  }
  __syncthreads();
  const float m = sh[T_STEPS];
  float e = __expf(l - m);
  __syncthreads();
  sh[t] = e;
  __syncthreads();
  for (int off = 1; off < T_STEPS; off <<= 1) {
    float v = (t >= off) ? sh[t - off] : 0.f;
    __syncthreads();
    sh[t] += v;
    __syncthreads();
  }
  const float total = sh[T_STEPS - 1];
  const float ts = sh[t] / total;

  float px[8], py[8], rr[8];
  #pragma unroll
  for (int n = 0; n < 8; ++n) {
    px[n] = ctrl[b * 16 + 2 * n];
    py[n] = ctrl[b * 16 + 2 * n + 1];
    rr[n] = ratw[b * 8 + n];
  }
  const float C[8] = {1.f, 7.f, 21.f, 35.f, 35.f, 21.f, 7.f, 1.f};
  float tp[8], up[8];
  tp[0] = 1.f; up[0] = 1.f;
  const float u = 1.f - ts;
  #pragma unroll
  for (int n = 1; n < 8; ++n) { tp[n] = tp[n - 1] * ts; up[n] = up[n - 1] * u; }
  float den = 0.f, nx = 0.f, ny = 0.f;
  #pragma unroll
  for (int n = 0; n < 8; ++n) {
    float w = C[n] * tp[n] * up[7 - n] * rr[n];
    den += w; nx += w * px[n]; ny += w * py[n];
  }
  out[(b * T_STEPS + t) * 2 + 0] = nx / den;
  out[(b * T_STEPS + t) * 2 + 1] = ny / den;

  if (b == 0) {   // regularizer scalar
    __syncthreads();
    if (t < BATCH) {
      float s2 = 0.f;
      #pragma unroll
      for (int n = 0; n < 7; ++n) {
        float dx = ctrl[t * 16 + 2 * n + 2] - ctrl[t * 16 + 2 * n + 0];
        float dy = ctrl[t * 16 + 2 * n + 3] - ctrl[t * 16 + 2 * n + 1];
        s2 += dx * dx + dy * dy;
      }
      sh[t] = s2;
    }
    __syncthreads();
    if (t == 0) {
      float tot = 0.f;
      for (int i = 0; i < BATCH; ++i) tot += sh[i];
      out[BATCH * T_STEPS * 2] = tot / (float)(BATCH * 7);
    }
  }
}

extern "C" void kernel_launch(void* const* d_in, const int* in_sizes, int n_in,
                              void* d_out, int out_size, void* d_ws, size_t ws_size,
                              hipStream_t stream)
{
  const float* x    = (const float*)d_in[0];
  const float* ctrl = (const float*)d_in[1];
  const float* ratw = (const float*)d_in[2];
  const float* Whf  = (const float*)d_in[3];
  const float* bhf  = (const float*)d_in[4];
  const float* Whb  = (const float*)d_in[5];
  const float* bhb  = (const float*)d_in[6];
  const float* Wcf  = (const float*)d_in[7];
  const float* bcf  = (const float*)d_in[8];
  const float* Wcb  = (const float*)d_in[9];
  const float* bcb  = (const float*)d_in[10];
  const float* Wihf = (const float*)d_in[11];
  const float* Whhf = (const float*)d_in[12];
  const float* bihf = (const float*)d_in[13];
  const float* bhhf = (const float*)d_in[14];
  const float* Wihb = (const float*)d_in[15];
  const float* Whhb = (const float*)d_in[16];
  const float* bihb = (const float*)d_in[17];
  const float* bhhb = (const float*)d_in[18];
  const float* Wlog = (const float*)d_in[19];
  float* out = (float*)d_out;
  char*  ws  = (char*)d_ws;
  if (ws_size < (size_t)WS_NEED) return;

  float*    logits = (float*)(ws + OFF_LOGITS);
  unsigned* bar    = (unsigned*)(ws + OFF_BAR);
  float*    c0     = (float*)(ws + OFF_C0);
  u16*      hb     = (u16*)(ws + OFF_H);
  u16*      wpack  = (u16*)(ws + OFF_WPACK);
  float*    coef   = (float*)(ws + OFF_COEF);

  hipMemsetAsync(ws, 0, MEMSET_BYTES, stream);
  pack_k<<<4096, 256, 0, stream>>>(Whhf, Whhb, wpack);
  coef_k<<<32, 256, 0, stream>>>(Wihf, bihf, bhhf, Wihb, bihb, bhhb, coef);
  init_k<<<dim3(768, 4), 256, 0, stream>>>(ctrl, ratw, Whf, bhf, Whb, bhb,
                                           Wcf, bcf, Wcb, bcb, hb, c0);
  hipFuncSetAttribute((const void*)lstm_persist,
                      hipFuncAttributeMaxDynamicSharedMemorySize, 158784);
  lstm_persist<<<NBLK, 256, 158784, stream>>>(x, Wlog, logits, c0, hb, wpack, coef, bar);
  post_k<<<BATCH, T_STEPS, 0, stream>>>(logits, ctrl, ratw, out);
}

// Round 2
// 6672.697 us; speedup vs baseline: 1.9984x; 1.9984x over previous
//
#include <hip/hip_runtime.h>
#include <stdint.h>

#define T_STEPS 320
#define BATCH   192
#define HID     1024
#define NBLK    256
#define NBLK_DIR 128

typedef unsigned short u16;
typedef __bf16 bf16x8 __attribute__((ext_vector_type(8)));
typedef float  f32x4  __attribute__((ext_vector_type(4)));
typedef unsigned int u32x4 __attribute__((ext_vector_type(4)));

// ---------------- workspace layout (bytes) ----------------
#define OFF_LOGITS   0u          // [192][320] f32 = 245760
#define OFF_BAR      245760u     // 2 x u32 monotonic barrier counters, 128B apart
#define MEMSET_BYTES 246016u
#define OFF_C0       262144u     // [2][192][1024] f32 = 1572864
#define OFF_H        1835008u    // [2 dir][2 buf][192][1024] bf16 = 1572864
#define OFF_WPACK    3407872u    // packed W_hh bf16 fragments = 16777216
#define OFF_COEF     20185088u   // [2][64][64] float4 (w0,w1,bias,0) = 131072
#define WS_NEED      20316160u

__device__ __forceinline__ u16 f2bf(float f) {
  unsigned u = __float_as_uint(f);
  unsigned r = (u + 0x7FFFu + ((u >> 16) & 1u)) >> 16;
  return (u16)r;
}
__device__ __forceinline__ float sigm(float x)   { return 1.f / (1.f + __expf(-x)); }
__device__ __forceinline__ float tanh_f(float x) { return 1.f - 2.f / (1.f + __expf(2.f * x)); }

// ---------------- prep: pack W_hh into MFMA-fragment order (bf16) ----------------
__global__ void pack_k(const float* __restrict__ Whhf, const float* __restrict__ Whhb,
                       u16* __restrict__ wpack)
{
  int lin = blockIdx.x * 256 + threadIdx.x;      // < 1048576
  int lane = lin & 63;
  int cg   = (lin >> 6) & 3;
  int ks   = (lin >> 8) & 31;
  int jsl  = (lin >> 13) & 63;
  int dir  = (lin >> 19) & 1;
  int col  = cg * 16 + (lane & 15);
  int R    = (col & 3) * 1024 + jsl * 16 + (col >> 2);
  int kb   = ks * 32 + (lane >> 4) * 8;
  const float* W = dir ? Whhb : Whhf;
  const float* src = W + (size_t)R * 1024 + kb;
  unsigned w[4];
  #pragma unroll
  for (int e = 0; e < 4; ++e) {
    unsigned lo = f2bf(src[2 * e]);
    unsigned hi = f2bf(src[2 * e + 1]);
    w[e] = lo | (hi << 16);
  }
  *((uint4*)(wpack + (size_t)lin * 8)) = make_uint4(w[0], w[1], w[2], w[3]);
}

// ---------------- prep: per-gate-row x-projection coefficients ----------------
__global__ void coef_k(const float* __restrict__ Wihf, const float* __restrict__ bihf,
                       const float* __restrict__ bhhf,
                       const float* __restrict__ Wihb, const float* __restrict__ bihb,
                       const float* __restrict__ bhhb, float* __restrict__ coef)
{
  int id  = blockIdx.x * 256 + threadIdx.x;      // < 8192
  int col = id & 63;
  int jsl = (id >> 6) & 63;
  int dir = (id >> 12) & 1;
  int R   = (col & 3) * 1024 + jsl * 16 + (col >> 2);
  const float* Wih = dir ? Wihb : Wihf;
  const float* bi  = dir ? bihb : bihf;
  const float* bh  = dir ? bhhb : bhhf;
  float4 v;
  v.x = Wih[(size_t)R * 2 + 0];
  v.y = Wih[(size_t)R * 2 + 1];
  v.z = bi[R] + bh[R];
  v.w = 0.f;
  ((float4*)coef)[id] = v;
}

// ---------------- prep: h0/c0 projections ----------------
__global__ void init_k(const float* __restrict__ ctrl, const float* __restrict__ ratw,
                       const float* __restrict__ Whf, const float* __restrict__ bhf,
                       const float* __restrict__ Whb, const float* __restrict__ bhb,
                       const float* __restrict__ Wcf, const float* __restrict__ bcf,
                       const float* __restrict__ Wcb, const float* __restrict__ bcb,
                       u16* hb, float* c0)
{
  int idx = blockIdx.x * 256 + threadIdx.x;      // 0..196607
  int m = blockIdx.y;                             // 0 h0f, 1 h0b, 2 c0f, 3 c0b
  int b = idx >> 10;
  int h = idx & 1023;
  const float* W  = (m == 0) ? Whf : (m == 1) ? Whb : (m == 2) ? Wcf : Wcb;
  const float* bi = (m == 0) ? bhf : (m == 1) ? bhb : (m == 2) ? bcf : bcb;
  float acc = bi[h];
  const float* wr = W + h * 24;
  #pragma unroll
  for (int k = 0; k < 16; ++k) acc += wr[k] * ctrl[b * 16 + k];
  #pragma unroll
  for (int k = 0; k < 8; ++k)  acc += wr[16 + k] * ratw[b * 8 + k];
  acc = tanh_f(acc);
  if (m < 2) hb[((size_t)(m * 2 + 0) * BATCH + b) * HID + h] = f2bf(acc);
  else       c0[((size_t)(m - 2) * BATCH + b) * HID + h] = acc;
}

// ---------------- persistent bi-LSTM ----------------
// sc0/sc1-bypass h exchange through L3; monotonic-counter grid barrier; no cache fences.
// A prefetch ring of 7 (depth 6, 18 loads in flight), counted vmcnt, sched_barrier pinning.

#define AL(s, OB) \
  asm volatile("global_load_dwordx4 %0, %1, off offset:" #OB " sc0 sc1" : "=v"(aq[s][0]) : "v"(ab0)); \
  asm volatile("global_load_dwordx4 %0, %1, off offset:" #OB " sc0 sc1" : "=v"(aq[s][1]) : "v"(ab1)); \
  asm volatile("global_load_dwordx4 %0, %1, off offset:" #OB " sc0 sc1" : "=v"(aq[s][2]) : "v"(ab2));

#define BL(s, KK) \
  bv[s][0] = *(const bf16x8*)(Wlds + (((KK) * 4 + wn2 + 0) * 64 + lane) * 8); \
  bv[s][1] = *(const bf16x8*)(Wlds + (((KK) * 4 + wn2 + 1) * 64 + lane) * 8);

#define WB(n) \
  asm volatile("s_waitcnt vmcnt(" #n ")" ::: "memory"); \
  __builtin_amdgcn_sched_barrier(0);

#define MM(s, p) { \
  bf16x8 aa0 = __builtin_bit_cast(bf16x8, aq[s][0]); \
  bf16x8 aa1 = __builtin_bit_cast(bf16x8, aq[s][1]); \
  bf16x8 aa2 = __builtin_bit_cast(bf16x8, aq[s][2]); \
  acc00 = __builtin_amdgcn_mfma_f32_16x16x32_bf16(aa0, bv[p][0], acc00, 0, 0, 0); \
  acc01 = __builtin_amdgcn_mfma_f32_16x16x32_bf16(aa0, bv[p][1], acc01, 0, 0, 0); \
  acc10 = __builtin_amdgcn_mfma_f32_16x16x32_bf16(aa1, bv[p][0], acc10, 0, 0, 0); \
  acc11 = __builtin_amdgcn_mfma_f32_16x16x32_bf16(aa1, bv[p][1], acc11, 0, 0, 0); \
  acc20 = __builtin_amdgcn_mfma_f32_16x16x32_bf16(aa2, bv[p][0], acc20, 0, 0, 0); \
  acc21 = __builtin_amdgcn_mfma_f32_16x16x32_bf16(aa2, bv[p][1], acc21, 0, 0, 0); \
}

#define HST(PT, VL) asm volatile("global_store_short %0, %1, off sc0 sc1" :: "v"(PT), "v"(VL) : "memory")

__launch_bounds__(256, 1)
__global__ void lstm_persist(const float* __restrict__ x,
                             const float* __restrict__ wlog,
                             float* logits,
                             const float* __restrict__ c0,
                             u16* hb,
                             const u16* __restrict__ wpack,
                             const float* __restrict__ coef,
                             unsigned* bar)
{
  extern __shared__ char lds[];
  u16*   Wlds = (u16*)lds;                    // [32 ks][4 cg][64 lane][8] bf16 = 128 KiB
  float* gbuf = (float*)(lds + 131072);       // [4 waves][48][36] f32 = 27648 B
  int*   ldsflag = (int*)(lds + 131072 + 27648);

  const int tid   = threadIdx.x;
  const int bid   = blockIdx.x;
  const int dir   = bid >> 7;
  const int bhalf = (bid >> 6) & 1;
  const int jsl   = bid & 63;
  const int wave  = tid >> 6;
  const int lane  = tid & 63;
  const int wm    = wave >> 1, wn = wave & 1;
  const int wn2   = wn * 2;

  if (tid == 0) *ldsflag = 0;

  { // W slice -> LDS once (read-only data, normal cached path)
    const uint4* wsrc = (const uint4*)wpack + (size_t)(dir * 64 + jsl) * 8192;
    uint4* wdst = (uint4*)Wlds;
    for (int i = tid; i < 8192; i += 256) wdst[i] = wsrc[i];
  }

  const int jj    = lane & 7;
  const int jglob = jsl * 16 + wn * 8 + jj;
  float4 cf0, cf1, cf2, cf3;
  {
    const float4* cp = (const float4*)coef + ((dir * 64 + jsl) * 64 + wn * 32 + jj * 4);
    cf0 = cp[0]; cf1 = cp[1]; cf2 = cp[2]; cf3 = cp[3];
  }
  const float wlg = wlog[dir * 1024 + jglob];

  float creg[6];
  int   bgl[6];
  #pragma unroll
  for (int i = 0; i < 6; ++i) {
    int q = lane + 64 * i;
    int b_loc = q >> 3;
    int bg = bhalf * 96 + wm * 48 + b_loc;
    bgl[i]  = bg;
    creg[i] = c0[((size_t)dir * BATCH + bg) * HID + jglob];
  }

  const int arow0 = bhalf * 96 + wm * 48 + 0 * 16 + (lane & 15);
  const int arow1 = arow0 + 16;
  const int arow2 = arow0 + 32;
  const int koff  = (lane >> 4) * 8;       // u16 units

  unsigned* cnt = bar + dir * 32;          // 128 B apart -> separate cache lines

  __syncthreads();

  for (int s = 0; s < T_STEPS; ++s) {
    const int rbuf = s & 1;
    const u16* hsrc = hb + ((size_t)(dir * 2 + rbuf)) * BATCH * HID;
    u16*       hdst = hb + ((size_t)(dir * 2 + (rbuf ^ 1))) * BATCH * HID;
    const u16* ab0 = hsrc + (size_t)arow0 * HID + koff;
    const u16* ab1 = hsrc + (size_t)arow1 * HID + koff;
    const u16* ab2 = hsrc + (size_t)arow2 * HID + koff;

    f32x4 acc00 = {0.f,0.f,0.f,0.f}, acc01 = {0.f,0.f,0.f,0.f};
    f32x4 acc10 = {0.f,0.f,0.f,0.f}, acc11 = {0.f,0.f,0.f,0.f};
    f32x4 acc20 = {0.f,0.f,0.f,0.f}, acc21 = {0.f,0.f,0.f,0.f};

    u32x4  aq[7][3];
    bf16x8 bv[3][2];

    // prologue: prefetch A(ks=0..5), B(0..1)
    AL(0, 0)   AL(1, 64)  AL(2, 128) AL(3, 192) AL(4, 256) AL(5, 320)
    BL(0, 0)   BL(1, 1)

    AL(6, 384)  BL(2, 2)  WB(18) MM(0, 0)
    AL(0, 448)  BL(0, 3)  WB(18) MM(1, 1)
    AL(1, 512)  BL(1, 4)  WB(18) MM(2, 2)
    AL(2, 576)  BL(2, 5)  WB(18) MM(3, 0)
    AL(3, 640)  BL(0, 6)  WB(18) MM(4, 1)
    AL(4, 704)  BL(1, 7)  WB(18) MM(5, 2)
    AL(5, 768)  BL(2, 8)  WB(18) MM(6, 0)
    AL(6, 832)  BL(0, 9)  WB(18) MM(0, 1)
    AL(0, 896)  BL(1, 10) WB(18) MM(1, 2)
    AL(1, 960)  BL(2, 11) WB(18) MM(2, 0)
    AL(2, 1024) BL(0, 12) WB(18) MM(3, 1)
    AL(3, 1088) BL(1, 13) WB(18) MM(4, 2)
    AL(4, 1152) BL(2, 14) WB(18) MM(5, 0)
    AL(5, 1216) BL(0, 15) WB(18) MM(6, 1)
    AL(6, 1280) BL(1, 16) WB(18) MM(0, 2)
    AL(0, 1344) BL(2, 17) WB(18) MM(1, 0)
    AL(1, 1408) BL(0, 18) WB(18) MM(2, 1)
    AL(2, 1472) BL(1, 19) WB(18) MM(3, 2)
    AL(3, 1536) BL(2, 20) WB(18) MM(4, 0)
    AL(4, 1600) BL(0, 21) WB(18) MM(5, 1)
    AL(5, 1664) BL(1, 22) WB(18) MM(6, 2)
    AL(6, 1728) BL(2, 23) WB(18) MM(0, 0)
    AL(0, 1792) BL(0, 24) WB(18) MM(1, 1)
    AL(1, 1856) BL(1, 25) WB(18) MM(2, 2)
    AL(2, 1920) BL(2, 26) WB(18) MM(3, 0)
    AL(3, 1984) BL(0, 27) WB(18) MM(4, 1)
                BL(1, 28) WB(15) MM(5, 2)
                BL(2, 29) WB(12) MM(6, 0)
                BL(0, 30) WB(9)  MM(0, 1)
                BL(1, 31) WB(6)  MM(1, 2)
                          WB(3)  MM(2, 0)
                          WB(0)  MM(3, 1)

    // D -> wave-local LDS transpose (rows: (lane>>4)*4+r, cols: lane&15)
    float* gb = gbuf + wave * (48 * 36);
    {
      const int rb = (lane >> 4) * 4;
      const int cl = lane & 15;
      #pragma unroll
      for (int r = 0; r < 4; ++r) {
        gb[(0  + rb + r) * 36 + 0  + cl] = acc00[r];
        gb[(0  + rb + r) * 36 + 16 + cl] = acc01[r];
        gb[(16 + rb + r) * 36 + 0  + cl] = acc10[r];
        gb[(16 + rb + r) * 36 + 16 + cl] = acc11[r];
        gb[(32 + rb + r) * 36 + 0  + cl] = acc20[r];
        gb[(32 + rb + r) * 36 + 16 + cl] = acc21[r];
      }
    }

    const int t_x = dir ? (T_STEPS - 1 - s) : s;

    #pragma unroll
    for (int i = 0; i < 6; ++i) {
      int q = lane + 64 * i;
      int b_loc = q >> 3;
      int bg = bgl[i];
      float4 g4 = *(const float4*)(gb + b_loc * 36 + jj * 4);   // (i,f,g,o)
      float2 xv = *(const float2*)(x + ((size_t)t_x * BATCH + bg) * 2);
      float pi = g4.x + cf0.x * xv.x + cf0.y * xv.y + cf0.z;
      float pf = g4.y + cf1.x * xv.x + cf1.y * xv.y + cf1.z;
      float pg = g4.z + cf2.x * xv.x + cf2.y * xv.y + cf2.z;
      float po = g4.w + cf3.x * xv.x + cf3.y * xv.y + cf3.z;
      float ig = sigm(pi), fg = sigm(pf), gv = tanh_f(pg), og = sigm(po);
      float c = fg * creg[i] + ig * gv;
      creg[i] = c;
      float h = og * tanh_f(c);
      u16* hp = hdst + (size_t)bg * HID + jglob;
      unsigned hv = (unsigned)f2bf(h);
      HST(hp, hv);
      float lp = h * wlg;
      lp += __shfl_xor(lp, 1);
      lp += __shfl_xor(lp, 2);
      lp += __shfl_xor(lp, 4);
      if (jj == 0) atomicAdd(&logits[bg * T_STEPS + t_x], lp);
    }

    // drain h stores (and atomics) to the coherence point, then barrier
    asm volatile("s_waitcnt vmcnt(0)" ::: "memory");
    __syncthreads();
    if (tid == 0) {
      const unsigned target = (unsigned)(s + 1) * NBLK_DIR;
      unsigned old = __hip_atomic_fetch_add(cnt, 1u, __ATOMIC_RELAXED, __HIP_MEMORY_SCOPE_AGENT);
      if (old != target - 1u) {
        long guard = 0;
        while (__hip_atomic_load(cnt, __ATOMIC_RELAXED, __HIP_MEMORY_SCOPE_AGENT) < target) {
          if (++guard > 1000000L) { *ldsflag = 1; break; }
        }
      }
    }
    __syncthreads();
    if (*ldsflag) return;   // co-residency failure: fail cleanly instead of hanging
  }
}

// ---------------- post: softmax -> cumsum -> rational Bezier -> curves + reg ----------------
__global__ void post_k(const float* __restrict__ logits, const float* __restrict__ ctrl,
                       const float* __restrict__ ratw, float* __restrict__ out)
{
  __shared__ float sh[T_STEPS + 64];
  const int b = blockIdx.x;
  const int t = threadIdx.x;          // 320 threads
  float l = logits[b * T_STEPS + t];
  sh[t] = l;
  __syncthreads();
  if (t < 64) {
    float mm = sh[t];
    for (int i = t + 64; i < T_STEPS; i += 64) mm = fmaxf(mm, sh[i]);
    #pragma unroll
    for (int o = 32; o; o >>= 1) mm = fmaxf(mm, __shfl_xor(mm, o));
    if (t == 0) sh[T_STEPS] = mm;
  }
  __syncthreads();
  const float m = sh[T_STEPS];
  float e = __expf(l - m);
  __syncthreads();
  sh[t] = e;
  __syncthreads();
  for (int off = 1; off < T_STEPS; off <<= 1) {
    float v = (t >= off) ? sh[t - off] : 0.f;
    __syncthreads();
    sh[t] += v;
    __syncthreads();
  }
  const float total = sh[T_STEPS - 1];
  const float ts = sh[t] / total;

  float px[8], py[8], rr[8];
  #pragma unroll
  for (int n = 0; n < 8; ++n) {
    px[n] = ctrl[b * 16 + 2 * n];
    py[n] = ctrl[b * 16 + 2 * n + 1];
    rr[n] = ratw[b * 8 + n];
  }
  const float C[8] = {1.f, 7.f, 21.f, 35.f, 35.f, 21.f, 7.f, 1.f};
  float tp[8], up[8];
  tp[0] = 1.f; up[0] = 1.f;
  const float u = 1.f - ts;
  #pragma unroll
  for (int n = 1; n < 8; ++n) { tp[n] = tp[n - 1] * ts; up[n] = up[n - 1] * u; }
  float den = 0.f, nx = 0.f, ny = 0.f;
  #pragma unroll
  for (int n = 0; n < 8; ++n) {
    float w = C[n] * tp[n] * up[7 - n] * rr[n];
    den += w; nx += w * px[n]; ny += w * py[n];
  }
  out[(b * T_STEPS + t) * 2 + 0] = nx / den;
  out[(b * T_STEPS + t) * 2 + 1] = ny / den;

  if (b == 0) {   // regularizer scalar
    __syncthreads();
    if (t < BATCH) {
      float s2 = 0.f;
      #pragma unroll
      for (int n = 0; n < 7; ++n) {
        float dx = ctrl[t * 16 + 2 * n + 2] - ctrl[t * 16 + 2 * n + 0];
        float dy = ctrl[t * 16 + 2 * n + 3] - ctrl[t * 16 + 2 * n + 1];
        s2 += dx * dx + dy * dy;
      }
      sh[t] = s2;
    }
    __syncthreads();
    if (t == 0) {
      float tot = 0.f;
      for (int i = 0; i < BATCH; ++i) tot += sh[i];
      out[BATCH * T_STEPS * 2] = tot / (float)(BATCH * 7);
    }
  }
}

extern "C" void kernel_launch(void* const* d_in, const int* in_sizes, int n_in,
                              void* d_out, int out_size, void* d_ws, size_t ws_size,
                              hipStream_t stream)
{
  const float* x    = (const float*)d_in[0];
  const float* ctrl = (const float*)d_in[1];
  const float* ratw = (const float*)d_in[2];
  const float* Whf  = (const float*)d_in[3];
  const float* bhf  = (const float*)d_in[4];
  const float* Whb  = (const float*)d_in[5];
  const float* bhb  = (const float*)d_in[6];
  const float* Wcf  = (const float*)d_in[7];
  const float* bcf  = (const float*)d_in[8];
  const float* Wcb  = (const float*)d_in[9];
  const float* bcb  = (const float*)d_in[10];
  const float* Wihf = (const float*)d_in[11];
  const float* Whhf = (const float*)d_in[12];
  const float* bihf = (const float*)d_in[13];
  const float* bhhf = (const float*)d_in[14];
  const float* Wihb = (const float*)d_in[15];
  const float* Whhb = (const float*)d_in[16];
  const float* bihb = (const float*)d_in[17];
  const float* bhhb = (const float*)d_in[18];
  const float* Wlog = (const float*)d_in[19];
  float* out = (float*)d_out;
  char*  ws  = (char*)d_ws;
  if (ws_size < (size_t)WS_NEED) return;

  float*    logits = (float*)(ws + OFF_LOGITS);
  unsigned* bar    = (unsigned*)(ws + OFF_BAR);
  float*    c0     = (float*)(ws + OFF_C0);
  u16*      hb     = (u16*)(ws + OFF_H);
  u16*      wpack  = (u16*)(ws + OFF_WPACK);
  float*    coef   = (float*)(ws + OFF_COEF);

  hipMemsetAsync(ws, 0, MEMSET_BYTES, stream);
  pack_k<<<4096, 256, 0, stream>>>(Whhf, Whhb, wpack);
  coef_k<<<32, 256, 0, stream>>>(Wihf, bihf, bhhf, Wihb, bihb, bhhb, coef);
  init_k<<<dim3(768, 4), 256, 0, stream>>>(ctrl, ratw, Whf, bhf, Whb, bhb,
                                           Wcf, bcf, Wcb, bcb, hb, c0);
  hipFuncSetAttribute((const void*)lstm_persist,
                      hipFuncAttributeMaxDynamicSharedMemorySize, 158784);
  lstm_persist<<<NBLK, 256, 158784, stream>>>(x, Wlog, logits, c0, hb, wpack, coef, bar);
  post_k<<<BATCH, T_STEPS, 0, stream>>>(logits, ctrl, ratw, out);
}

// Round 3
// 6149.393 us; speedup vs baseline: 2.1685x; 1.0851x over previous
//
#include <hip/hip_runtime.h>
#include <stdint.h>

#define T_STEPS 320
#define BATCH   192
#define HID     1024
#define NBLK    256
#define NBLK_DIR 128

typedef unsigned short u16;
typedef __bf16 bf16x8 __attribute__((ext_vector_type(8)));
typedef float  f32x4  __attribute__((ext_vector_type(4)));
typedef unsigned int u32x4 __attribute__((ext_vector_type(4)));

// ---------------- workspace layout (bytes) ----------------
#define OFF_LOGITS   0u          // [192][320] f32 = 245760
#define OFF_BAR      245760u     // 2 x u32 monotonic barrier counters, 128B apart
#define MEMSET_BYTES 246016u
#define OFF_C0       262144u     // [2][192][1024] f32 = 1572864
#define OFF_H        1835008u    // [2 dir][2 buf][192][1024] bf16 = 1572864
#define OFF_WPACK    3407872u    // packed W_hh bf16 fragments = 16777216
#define OFF_COEF     20185088u   // [2][64][64] float4 (w0,w1,bias,0) = 131072
#define WS_NEED      20316160u

__device__ __forceinline__ u16 f2bf(float f) {
  unsigned u = __float_as_uint(f);
  unsigned r = (u + 0x7FFFu + ((u >> 16) & 1u)) >> 16;
  return (u16)r;
}
__device__ __forceinline__ float sigm(float x)   { return 1.f / (1.f + __expf(-x)); }
__device__ __forceinline__ float tanh_f(float x) { return 1.f - 2.f / (1.f + __expf(2.f * x)); }

// ---------------- prep: pack W_hh into MFMA-fragment order (bf16) ----------------
__global__ void pack_k(const float* __restrict__ Whhf, const float* __restrict__ Whhb,
                       u16* __restrict__ wpack)
{
  int lin = blockIdx.x * 256 + threadIdx.x;      // < 1048576
  int lane = lin & 63;
  int cg   = (lin >> 6) & 3;
  int ks   = (lin >> 8) & 31;
  int jsl  = (lin >> 13) & 63;
  int dir  = (lin >> 19) & 1;
  int col  = cg * 16 + (lane & 15);
  int R    = (col & 3) * 1024 + jsl * 16 + (col >> 2);
  int kb   = ks * 32 + (lane >> 4) * 8;
  const float* W = dir ? Whhb : Whhf;
  const float* src = W + (size_t)R * 1024 + kb;
  unsigned w[4];
  #pragma unroll
  for (int e = 0; e < 4; ++e) {
    unsigned lo = f2bf(src[2 * e]);
    unsigned hi = f2bf(src[2 * e + 1]);
    w[e] = lo | (hi << 16);
  }
  *((uint4*)(wpack + (size_t)lin * 8)) = make_uint4(w[0], w[1], w[2], w[3]);
}

// ---------------- prep: per-gate-row x-projection coefficients ----------------
__global__ void coef_k(const float* __restrict__ Wihf, const float* __restrict__ bihf,
                       const float* __restrict__ bhhf,
                       const float* __restrict__ Wihb, const float* __restrict__ bihb,
                       const float* __restrict__ bhhb, float* __restrict__ coef)
{
  int id  = blockIdx.x * 256 + threadIdx.x;      // < 8192
  int col = id & 63;
  int jsl = (id >> 6) & 63;
  int dir = (id >> 12) & 1;
  int R   = (col & 3) * 1024 + jsl * 16 + (col >> 2);
  const float* Wih = dir ? Wihb : Wihf;
  const float* bi  = dir ? bihb : bihf;
  const float* bh  = dir ? bhhb : bhhf;
  float4 v;
  v.x = Wih[(size_t)R * 2 + 0];
  v.y = Wih[(size_t)R * 2 + 1];
  v.z = bi[R] + bh[R];
  v.w = 0.f;
  ((float4*)coef)[id] = v;
}

// ---------------- prep: h0/c0 projections ----------------
__global__ void init_k(const float* __restrict__ ctrl, const float* __restrict__ ratw,
                       const float* __restrict__ Whf, const float* __restrict__ bhf,
                       const float* __restrict__ Whb, const float* __restrict__ bhb,
                       const float* __restrict__ Wcf, const float* __restrict__ bcf,
                       const float* __restrict__ Wcb, const float* __restrict__ bcb,
                       u16* hb, float* c0)
{
  int idx = blockIdx.x * 256 + threadIdx.x;      // 0..196607
  int m = blockIdx.y;                             // 0 h0f, 1 h0b, 2 c0f, 3 c0b
  int b = idx >> 10;
  int h = idx & 1023;
  const float* W  = (m == 0) ? Whf : (m == 1) ? Whb : (m == 2) ? Wcf : Wcb;
  const float* bi = (m == 0) ? bhf : (m == 1) ? bhb : (m == 2) ? bcf : bcb;
  float acc = bi[h];
  const float* wr = W + h * 24;
  #pragma unroll
  for (int k = 0; k < 16; ++k) acc += wr[k] * ctrl[b * 16 + k];
  #pragma unroll
  for (int k = 0; k < 8; ++k)  acc += wr[16 + k] * ratw[b * 8 + k];
  acc = tanh_f(acc);
  if (m < 2) hb[((size_t)(m * 2 + 0) * BATCH + b) * HID + h] = f2bf(acc);
  else       c0[((size_t)(m - 2) * BATCH + b) * HID + h] = acc;
}

// ---------------- persistent bi-LSTM, 8 waves (2/SIMD), K split across wave pairs ----------------
// block: dir = bid>>7, bhalf = (bid>>6)&1, jsl = bid&63. 512 threads.
// wave w = wm*4 + wn*2 + wk: wm rows-48-half, wn cols-32-half, wk K-512-half.

#define AL(s, OB) \
  asm volatile("global_load_dwordx4 %0, %1, off offset:" #OB " sc0 sc1" : "=v"(aq[s][0]) : "v"(ab0)); \
  asm volatile("global_load_dwordx4 %0, %1, off offset:" #OB " sc0 sc1" : "=v"(aq[s][1]) : "v"(ab1)); \
  asm volatile("global_load_dwordx4 %0, %1, off offset:" #OB " sc0 sc1" : "=v"(aq[s][2]) : "v"(ab2));

#define BL(s, KK) \
  bv[s][0] = *(const bf16x8*)(bW + (KK) * 2048); \
  bv[s][1] = *(const bf16x8*)(bW + (KK) * 2048 + 512);

#define WB(n) \
  asm volatile("s_waitcnt vmcnt(" #n ")" ::: "memory"); \
  __builtin_amdgcn_sched_barrier(0);

#define MM(s, p) { \
  _Pragma("unroll") \
  for (int mt_ = 0; mt_ < 3; ++mt_) { \
    bf16x8 a_ = __builtin_bit_cast(bf16x8, aq[s][mt_]); \
    acc[mt_][0] = __builtin_amdgcn_mfma_f32_16x16x32_bf16(a_, bv[p][0], acc[mt_][0], 0, 0, 0); \
    acc[mt_][1] = __builtin_amdgcn_mfma_f32_16x16x32_bf16(a_, bv[p][1], acc[mt_][1], 0, 0, 0); \
  } \
}

#define HST(PT, VL) asm volatile("global_store_short %0, %1, off sc0 sc1" :: "v"(PT), "v"(VL) : "memory")

__launch_bounds__(512, 1)
__global__ void lstm_persist(const float* __restrict__ x,
                             const float* __restrict__ wlog,
                             float* logits,
                             const float* __restrict__ c0,
                             u16* hb,
                             const u16* __restrict__ wpack,
                             const float* __restrict__ coef,
                             unsigned* bar)
{
  extern __shared__ char lds[];
  u16*   Wlds = (u16*)lds;                    // [32 ks][4 cg][64 lane][8] bf16 = 128 KiB
  float* DMP  = (float*)(lds + 131072);       // [8 regions][8 q][64 lane] f32 = 16 KiB
  int*   ldsflag = (int*)(lds + 131072 + 16384);

  const int tid   = threadIdx.x;
  const int bid   = blockIdx.x;
  const int dir   = bid >> 7;
  const int bhalf = (bid >> 6) & 1;
  const int jsl   = bid & 63;
  const int wave  = tid >> 6;
  const int lane  = tid & 63;
  const int wm    = wave >> 2;
  const int wn    = (wave >> 1) & 1;
  const int wk    = wave & 1;
  const int wn2   = wn * 2;
  const int pairR = (wm * 2 + wn) * 2;        // region pair base (wk0, wk1 = +1)

  if (tid == 0) *ldsflag = 0;

  { // W slice -> LDS once (read-only, normal cached path)
    const uint4* wsrc = (const uint4*)wpack + (size_t)(dir * 64 + jsl) * 8192;
    uint4* wdst = (uint4*)Wlds;
    for (int i = tid; i < 8192; i += 512) wdst[i] = wsrc[i];
  }

  const int jj    = lane & 7;
  const int jglob = jsl * 16 + wn * 8 + jj;
  float4 cf0, cf1, cf2, cf3;
  {
    const float4* cp = (const float4*)coef + ((dir * 64 + jsl) * 64 + wn * 32 + jj * 4);
    cf0 = cp[0]; cf1 = cp[1]; cf2 = cp[2]; cf3 = cp[3];
  }
  const float wlg = wlog[dir * 1024 + jglob];

  // pointwise ownership: this wave handles row-blocks mt=0..2, rows b_loc = 16*mt + 8*wk + (lane>>3)
  const int bsub = lane >> 3;                 // 0..7
  float creg[3];
  int   bgm[3];
  #pragma unroll
  for (int mt = 0; mt < 3; ++mt) {
    int b_loc = 16 * mt + 8 * wk + bsub;
    int bg = bhalf * 96 + wm * 48 + b_loc;
    bgm[mt] = bg;
    creg[mt] = c0[((size_t)dir * BATCH + bg) * HID + jglob];
  }

  const int arow0 = bhalf * 96 + wm * 48 + 0 * 16 + (lane & 15);
  const int arow1 = arow0 + 16;
  const int arow2 = arow0 + 32;
  const int koff  = wk * 512 + (lane >> 4) * 8;   // u16 units

  const u16* bW = Wlds + ((size_t)(wk * 64 + wn2) * 64 + lane) * 8;

  unsigned* cnt = bar + dir * 32;             // 128 B apart -> separate cache lines

  __syncthreads();

  for (int s = 0; s < T_STEPS; ++s) {
    const int rbuf = s & 1;
    const u16* hsrc = hb + ((size_t)(dir * 2 + rbuf)) * BATCH * HID;
    u16*       hdst = hb + ((size_t)(dir * 2 + (rbuf ^ 1))) * BATCH * HID;
    const u16* ab0 = hsrc + (size_t)arow0 * HID + koff;
    const u16* ab1 = hsrc + (size_t)arow1 * HID + koff;
    const u16* ab2 = hsrc + (size_t)arow2 * HID + koff;

    f32x4 acc[3][2];
    #pragma unroll
    for (int mt = 0; mt < 3; ++mt) {
      acc[mt][0] = (f32x4){0.f, 0.f, 0.f, 0.f};
      acc[mt][1] = (f32x4){0.f, 0.f, 0.f, 0.f};
    }

    u32x4  aq[6][3];
    bf16x8 bv[3][2];

    // 16 K-iterations (K=512 per wave), ring-6 A prefetch (15-18 outstanding), ring-3 B
    AL(0, 0)   AL(1, 64)  AL(2, 128) AL(3, 192) AL(4, 256)
    BL(0, 0)   BL(1, 1)

    AL(5, 320) BL(2, 2)   WB(15) MM(0, 0)
    AL(0, 384) BL(0, 3)   WB(15) MM(1, 1)
    AL(1, 448) BL(1, 4)   WB(15) MM(2, 2)
    AL(2, 512) BL(2, 5)   WB(15) MM(3, 0)
    AL(3, 576) BL(0, 6)   WB(15) MM(4, 1)
    AL(4, 640) BL(1, 7)   WB(15) MM(5, 2)
    AL(5, 704) BL(2, 8)   WB(15) MM(0, 0)
    AL(0, 768) BL(0, 9)   WB(15) MM(1, 1)
    AL(1, 832) BL(1, 10)  WB(15) MM(2, 2)
    AL(2, 896) BL(2, 11)  WB(15) MM(3, 0)
    AL(3, 960) BL(0, 12)  WB(15) MM(4, 1)
               BL(1, 13)  WB(12) MM(5, 2)
               BL(2, 14)  WB(9)  MM(0, 0)
               BL(0, 15)  WB(6)  MM(1, 1)
                          WB(3)  MM(2, 2)
                          WB(0)  MM(3, 0)

    const int t_x = dir ? (T_STEPS - 1 - s) : s;

    // 3 row-block phases: dump raw acc -> sync -> gather own+partner K-half -> pointwise
    #pragma unroll
    for (int mt = 0; mt < 3; ++mt) {
      // dump: region (pairR + wk), layout [q = cgi*4+reg][lane], conflict-free
      float* myreg = DMP + (pairR + wk) * 512;
      #pragma unroll
      for (int cgi = 0; cgi < 2; ++cgi)
        #pragma unroll
        for (int r = 0; r < 4; ++r)
          myreg[(cgi * 4 + r) * 64 + lane] = acc[mt][cgi][r];
      __syncthreads();

      // gather element (b_loc, jj, g) from both wk regions.
      // C/D layout: col = lane&15 = (jj&3)*4+g, row = (lane>>4)*4+reg, reg = b_loc&3
      {
        int b_loc = 16 * mt + 8 * wk + bsub;
        int bg    = bgm[mt];
        int q4    = (jj >> 2) * 4 + (bsub & 3);
        int off   = q4 * 64 + ((8 * wk + (bsub & 4)) << 2) + (jj & 3) * 4;
        const f32x4 pa = *(const f32x4*)(DMP + pairR * 512 + off);
        const f32x4 pb = *(const f32x4*)(DMP + (pairR + 1) * 512 + off);
        float gi = pa[0] + pb[0];
        float gf = pa[1] + pb[1];
        float gg = pa[2] + pb[2];
        float go = pa[3] + pb[3];
        float2 xv = *(const float2*)(x + ((size_t)t_x * BATCH + bg) * 2);
        float pi = gi + cf0.x * xv.x + cf0.y * xv.y + cf0.z;
        float pf = gf + cf1.x * xv.x + cf1.y * xv.y + cf1.z;
        float pg = gg + cf2.x * xv.x + cf2.y * xv.y + cf2.z;
        float po = go + cf3.x * xv.x + cf3.y * xv.y + cf3.z;
        float ig = sigm(pi), fg = sigm(pf), gv = tanh_f(pg), og = sigm(po);
        float c = fg * creg[mt] + ig * gv;
        creg[mt] = c;
        float h = og * tanh_f(c);
        u16* hp = hdst + (size_t)bg * HID + jglob;
        unsigned hv = (unsigned)f2bf(h);
        HST(hp, hv);
        float lp = h * wlg;
        lp += __shfl_xor(lp, 1);
        lp += __shfl_xor(lp, 2);
        lp += __shfl_xor(lp, 4);
        if (jj == 0) atomicAdd(&logits[bg * T_STEPS + t_x], lp);
        (void)b_loc;
      }
      __syncthreads();   // protect DMP before next mt overwrites
    }

    // drain h stores + atomics to coherence point, then per-direction barrier
    asm volatile("s_waitcnt vmcnt(0)" ::: "memory");
    __syncthreads();
    if (tid == 0) {
      const unsigned target = (unsigned)(s + 1) * NBLK_DIR;
      unsigned old = __hip_atomic_fetch_add(cnt, 1u, __ATOMIC_RELAXED, __HIP_MEMORY_SCOPE_AGENT);
      if (old != target - 1u) {
        long guard = 0;
        while (__hip_atomic_load(cnt, __ATOMIC_RELAXED, __HIP_MEMORY_SCOPE_AGENT) < target) {
          if (++guard > 1000000L) { *ldsflag = 1; break; }
        }
      }
    }
    __syncthreads();
    if (*ldsflag) return;   // co-residency failure: fail cleanly instead of hanging
  }
}

// ---------------- post: softmax -> cumsum -> rational Bezier -> curves + reg ----------------
__global__ void post_k(const float* __restrict__ logits, const float* __restrict__ ctrl,
                       const float* __restrict__ ratw, float* __restrict__ out)
{
  __shared__ float sh[T_STEPS + 64];
  const int b = blockIdx.x;
  const int t = threadIdx.x;          // 320 threads
  float l = logits[b * T_STEPS + t];
  sh[t] = l;
  __syncthreads();
  if (t < 64) {
    float mm = sh[t];
    for (int i = t + 64; i < T_STEPS; i += 64) mm = fmaxf(mm, sh[i]);
    #pragma unroll
    for (int o = 32; o; o >>= 1) mm = fmaxf(mm, __shfl_xor(mm, o));
    if (t == 0) sh[T_STEPS] = mm;
  }
  __syncthreads();
  const float m = sh[T_STEPS];
  float e = __expf(l - m);
  __syncthreads();
  sh[t] = e;
  __syncthreads();
  for (int off = 1; off < T_STEPS; off <<= 1) {
    float v = (t >= off) ? sh[t - off] : 0.f;
    __syncthreads();
    sh[t] += v;
    __syncthreads();
  }
  const float total = sh[T_STEPS - 1];
  const float ts = sh[t] / total;

  float px[8], py[8], rr[8];
  #pragma unroll
  for (int n = 0; n < 8; ++n) {
    px[n] = ctrl[b * 16 + 2 * n];
    py[n] = ctrl[b * 16 + 2 * n + 1];
    rr[n] = ratw[b * 8 + n];
  }
  const float C[8] = {1.f, 7.f, 21.f, 35.f, 35.f, 21.f, 7.f, 1.f};
  float tp[8], up[8];
  tp[0] = 1.f; up[0] = 1.f;
  const float u = 1.f - ts;
  #pragma unroll
  for (int n = 1; n < 8; ++n) { tp[n] = tp[n - 1] * ts; up[n] = up[n - 1] * u; }
  float den = 0.f, nx = 0.f, ny = 0.f;
  #pragma unroll
  for (int n = 0; n < 8; ++n) {
    float w = C[n] * tp[n] * up[7 - n] * rr[n];
    den += w; nx += w * px[n]; ny += w * py[n];
  }
  out[(b * T_STEPS + t) * 2 + 0] = nx / den;
  out[(b * T_STEPS + t) * 2 + 1] = ny / den;

  if (b == 0) {   // regularizer scalar
    __syncthreads();
    if (t < BATCH) {
      float s2 = 0.f;
      #pragma unroll
      for (int n = 0; n < 7; ++n) {
        float dx = ctrl[t * 16 + 2 * n + 2] - ctrl[t * 16 + 2 * n + 0];
        float dy = ctrl[t * 16 + 2 * n + 3] - ctrl[t * 16 + 2 * n + 1];
        s2 += dx * dx + dy * dy;
      }
      sh[t] = s2;
    }
    __syncthreads();
    if (t == 0) {
      float tot = 0.f;
      for (int i = 0; i < BATCH; ++i) tot += sh[i];
      out[BATCH * T_STEPS * 2] = tot / (float)(BATCH * 7);
    }
  }
}

extern "C" void kernel_launch(void* const* d_in, const int* in_sizes, int n_in,
                              void* d_out, int out_size, void* d_ws, size_t ws_size,
                              hipStream_t stream)
{
  const float* x    = (const float*)d_in[0];
  const float* ctrl = (const float*)d_in[1];
  const float* ratw = (const float*)d_in[2];
  const float* Whf  = (const float*)d_in[3];
  const float* bhf  = (const float*)d_in[4];
  const float* Whb  = (const float*)d_in[5];
  const float* bhb  = (const float*)d_in[6];
  const float* Wcf  = (const float*)d_in[7];
  const float* bcf  = (const float*)d_in[8];
  const float* Wcb  = (const float*)d_in[9];
  const float* bcb  = (const float*)d_in[10];
  const float* Wihf = (const float*)d_in[11];
  const float* Whhf = (const float*)d_in[12];
  const float* bihf = (const float*)d_in[13];
  const float* bhhf = (const float*)d_in[14];
  const float* Wihb = (const float*)d_in[15];
  const float* Whhb = (const float*)d_in[16];
  const float* bihb = (const float*)d_in[17];
  const float* bhhb = (const float*)d_in[18];
  const float* Wlog = (const float*)d_in[19];
  float* out = (float*)d_out;
  char*  ws  = (char*)d_ws;
  if (ws_size < (size_t)WS_NEED) return;

  float*    logits = (float*)(ws + OFF_LOGITS);
  unsigned* bar    = (unsigned*)(ws + OFF_BAR);
  float*    c0     = (float*)(ws + OFF_C0);
  u16*      hb     = (u16*)(ws + OFF_H);
  u16*      wpack  = (u16*)(ws + OFF_WPACK);
  float*    coef   = (float*)(ws + OFF_COEF);

  hipMemsetAsync(ws, 0, MEMSET_BYTES, stream);
  pack_k<<<4096, 256, 0, stream>>>(Whhf, Whhb, wpack);
  coef_k<<<32, 256, 0, stream>>>(Wihf, bihf, bhhf, Wihb, bihb, bhhb, coef);
  init_k<<<dim3(768, 4), 256, 0, stream>>>(ctrl, ratw, Whf, bhf, Whb, bhb,
                                           Wcf, bcf, Wcb, bcb, hb, c0);
  hipFuncSetAttribute((const void*)lstm_persist,
                      hipFuncAttributeMaxDynamicSharedMemorySize, 147472);
  lstm_persist<<<NBLK, 512, 147472, stream>>>(x, Wlog, logits, c0, hb, wpack, coef, bar);
  post_k<<<BATCH, T_STEPS, 0, stream>>>(logits, ctrl, ratw, out);
}